// Round 9
// baseline (653.770 us; speedup 1.0000x reference)
//
#include <hip/hip_runtime.h>

typedef __attribute__((ext_vector_type(8))) short short8;
typedef __attribute__((ext_vector_type(8))) unsigned short ushort8;
typedef __attribute__((ext_vector_type(4))) float f32x4;

#define DEV __device__ __forceinline__

DEV unsigned short f2bf(float f) {
  unsigned int u = __float_as_uint(f);
  u += 0x7fffu + ((u >> 16) & 1u);
  return (unsigned short)(u >> 16);
}
DEV float sigm(float x) { return 1.f / (1.f + __expf(-x)); }
DEV float tanh_(float x) { return 1.f - 2.f / (1.f + __expf(2.f * x)); }

typedef __attribute__((address_space(1))) const void* as1cv;
typedef __attribute__((address_space(3))) void* as3v;
DEV void gll16(const void* g, void* l) {
  __builtin_amdgcn_global_load_lds((as1cv)g, (as3v)l, 16, 0, 0);
}

// ---- k_pre: block 0 = sort + gathers + packing meta (+xsb, bar=0); blocks 1.. =
// weight conversions Wpro(3072x512) | Wihb2(2048x256) | Whb(2048x512) ------------
__global__ void __launch_bounds__(256) k_pre(const float* __restrict__ x,
    const int* __restrict__ ptar, const int* __restrict__ tlen,
    const float* __restrict__ W_h0, const float* __restrict__ W_c0,
    const float* __restrict__ W_ih, const float* __restrict__ W_hh,
    int* __restrict__ sidx, int* __restrict__ lens, int* __restrict__ base,
    int* __restrict__ inv, int* __restrict__ Pw, int* __restrict__ tok,
    unsigned short* __restrict__ xsb, float* __restrict__ tail,
    unsigned short* __restrict__ Wpro, unsigned short* __restrict__ Wihb2,
    unsigned short* __restrict__ Whb, int* __restrict__ bar) {
  int bid = blockIdx.x, tid = threadIdx.x;
  if (bid > 0) {  // weight conversions (independent of sort)
    long long g = (long long)(bid - 1) * 2048 + tid * 8;
    const float* src;
    unsigned short* dst;
    if (g < 262144) {                       // W_h0 -> Wpro[0:512]
      src = W_h0 + g; dst = Wpro + g;
    } else if (g < 524288) {                // W_c0 -> Wpro[512:1024]
      long long l = g - 262144; src = W_c0 + l; dst = Wpro + 262144 + l;
    } else if (g < 1572864) {               // W_ih[:, :512] -> Wpro[1024:3072]
      long long l = g - 524288;
      long long r = l >> 9, c = l & 511;
      src = W_ih + r * 768 + c; dst = Wpro + 524288 + l;
    } else if (g < 2097152) {               // W_ih[:, 512:768] -> Wihb2
      long long l = g - 1572864;
      long long r = l >> 8, c = l & 255;
      src = W_ih + r * 768 + 512 + c; dst = Wihb2 + l;
    } else {                                // W_hh -> Whb
      long long l = g - 2097152; src = W_hh + l; dst = Whb + l;
    }
    float4 v0 = *(const float4*)src, v1 = *(const float4*)(src + 4);
    ushort8 o;
    o[0] = f2bf(v0.x); o[1] = f2bf(v0.y); o[2] = f2bf(v0.z); o[3] = f2bf(v0.w);
    o[4] = f2bf(v1.x); o[5] = f2bf(v1.y); o[6] = f2bf(v1.z); o[7] = f2bf(v1.w);
    *(ushort8*)dst = o;
    return;
  }
  __shared__ int ss[64], ls[64], bs[64];
  if (tid < 32) bar[tid] = 0;  // persistent-step barrier counters
  if (tid < 64) {
    int li = tlen[tid];
    int rank = 0;
    for (int j = 0; j < 64; ++j) {
      int lj = tlen[j];
      rank += (lj > li || (lj == li && j < tid)) ? 1 : 0;
    }
    ss[rank] = tid;
  }
  __syncthreads();
  if (tid < 64) {
    int src = ss[tid];
    sidx[tid] = src;
    int l = tlen[src] - 1;
    ls[tid] = l;
    lens[tid] = l;
    tail[tid] = (float)src;
  }
  __syncthreads();
  if (tid == 0) {
    int s = 0;
    for (int b = 0; b < 64; ++b) { bs[b] = s; base[b] = s; s += ls[b]; }
    Pw[0] = s;
  }
  __syncthreads();
  for (int idx = tid; idx < 2048; idx += 256) {
    int b = idx >> 5, t = idx & 31;
    if (t < ls[b]) inv[bs[b] + t] = idx;
  }
  for (int idx = tid; idx < 32 * 64; idx += 256) {
    int t = idx >> 6, b = idx & 63;
    tok[idx] = ptar[ss[b] * 33 + t];
  }
  for (int idx = tid; idx < 64 * 512; idx += 256) {
    int b = idx >> 9;
    xsb[idx] = f2bf(x[ss[b] * 512 + (idx & 511)]);
  }
}

// ---- k_mid: blocks 0..47 = prologue GEMM (h0/c0/gx); blocks 48..303 = embedding
// gather -> bf16 Eb[2048][256] ----------------------------------------------------
__global__ void __launch_bounds__(256) k_mid(const unsigned short* __restrict__ xsb,
    const unsigned short* __restrict__ Wpro, const float* __restrict__ b_h0,
    const float* __restrict__ b_c0, const float* __restrict__ b_ih,
    const float* __restrict__ b_hh, unsigned short* __restrict__ h0b,
    float* __restrict__ c, float* __restrict__ gx,
    const int* __restrict__ tok, const float* __restrict__ embed,
    unsigned short* __restrict__ Eb) {
  int bid = blockIdx.x, tid = threadIdx.x;
  if (bid >= 48) {  // embedding gather
    int gid = (bid - 48) * 256 + tid;
    int row = gid >> 5, c8 = (gid & 31) * 8;
    const float* src = embed + (size_t)tok[row] * 256 + c8;
    float4 v0 = *(const float4*)src, v1 = *(const float4*)(src + 4);
    ushort8 o;
    o[0] = f2bf(v0.x); o[1] = f2bf(v0.y); o[2] = f2bf(v0.z); o[3] = f2bf(v0.w);
    o[4] = f2bf(v1.x); o[5] = f2bf(v1.y); o[6] = f2bf(v1.z); o[7] = f2bf(v1.w);
    *(ushort8*)(Eb + (size_t)row * 256 + c8) = o;
    return;
  }
  int lane = tid & 63, w = tid >> 6;
  int n0 = bid * 64 + w * 16;
  int lr = lane & 15, lk = lane >> 4;
  f32x4 acc[4];
#pragma unroll
  for (int i = 0; i < 4; ++i) acc[i] = (f32x4){0.f, 0.f, 0.f, 0.f};
  const unsigned short* B = Wpro + (size_t)(n0 + lr) * 512 + lk * 8;
  const unsigned short* A = xsb + (size_t)lr * 512 + lk * 8;
#pragma unroll
  for (int ks = 0; ks < 16; ++ks) {
    short8 bfr = *(const short8*)(B + ks * 32);
#pragma unroll
    for (int mi = 0; mi < 4; ++mi) {
      short8 af = *(const short8*)(A + mi * 16 * 512 + ks * 32);
      acc[mi] = __builtin_amdgcn_mfma_f32_16x16x32_bf16(af, bfr, acc[mi], 0, 0, 0);
    }
  }
  int n = n0 + lr;
#pragma unroll
  for (int mi = 0; mi < 4; ++mi)
#pragma unroll
    for (int r = 0; r < 4; ++r) {
      int b = mi * 16 + lk * 4 + r;
      float v = acc[mi][r];
      if (n < 512) {
        h0b[b * 512 + n] = f2bf(v + b_h0[n]);
      } else if (n < 1024) {
        int u = n - 512;
        c[b * 512 + u] = v + b_c0[u];
      } else {
        int j = n - 1024;
        gx[(size_t)b * 2048 + j] = v + b_ih[j] + b_hh[j];
      }
    }
}

// ---- GA[m][j] = Eb[m].Wihb2[j] + gx[m&63][j]   (2048x2048, K=256) --------------
__global__ void __launch_bounds__(256) k_ga2(const unsigned short* __restrict__ Eb,
    const unsigned short* __restrict__ Wb2, const float* __restrict__ gx,
    float* __restrict__ GA) {
  __shared__ alignas(16) char ldsbuf[32768];
  char* ldsA = ldsbuf;
  char* ldsB = ldsbuf + 16384;
  int bid = blockIdx.x, tid = threadIdx.x;
  int mt = bid & 15, nt = bid >> 4;
  int m0 = mt * 128, n0 = nt * 128;
  int lane = tid & 63, w = tid >> 6;
  int wm = w >> 1, wn = w & 1;
  f32x4 acc[4][4];
#pragma unroll
  for (int a = 0; a < 4; ++a)
#pragma unroll
    for (int bq = 0; bq < 4; ++bq) acc[a][bq] = (f32x4){0.f, 0.f, 0.f, 0.f};
  const unsigned short* Arow = Eb + (size_t)m0 * 256;
  const unsigned short* Brow = Wb2 + (size_t)n0 * 256;
  for (int kt = 0; kt < 4; ++kt) {
    int k0 = kt * 64;
    if (kt) __syncthreads();
#pragma unroll
    for (int j = 0; j < 4; ++j) {
      int ci = j * 256 + w * 64 + lane;
      int r = ci >> 3;
      int clog = ((ci & 7) << 4) ^ ((r & 7) << 4);
      int ldst = (j * 256 + w * 64) * 16;
      gll16((const char*)(Arow + (size_t)r * 256 + k0) + clog, ldsA + ldst);
      gll16((const char*)(Brow + (size_t)r * 256 + k0) + clog, ldsB + ldst);
    }
    __syncthreads();
#pragma unroll
    for (int kk = 0; kk < 2; ++kk) {
      short8 af[4], bf[4];
      int cb = kk * 64 + (lane >> 4) * 16;
#pragma unroll
      for (int i = 0; i < 4; ++i) {
        int ar = wm * 64 + i * 16 + (lane & 15);
        af[i] = *(const short8*)(ldsA + ar * 128 + (cb ^ ((ar & 7) << 4)));
        int br = wn * 64 + i * 16 + (lane & 15);
        bf[i] = *(const short8*)(ldsB + br * 128 + (cb ^ ((br & 7) << 4)));
      }
#pragma unroll
      for (int mi = 0; mi < 4; ++mi)
#pragma unroll
        for (int ni = 0; ni < 4; ++ni)
          acc[mi][ni] = __builtin_amdgcn_mfma_f32_16x16x32_bf16(
              af[mi], bf[ni], acc[mi][ni], 0, 0, 0);
    }
  }
#pragma unroll
  for (int mi = 0; mi < 4; ++mi) {
    int mb = m0 + wm * 64 + mi * 16 + ((lane >> 4) << 2);
#pragma unroll
    for (int r = 0; r < 4; ++r) {
      int m = mb + r;
#pragma unroll
      for (int ni = 0; ni < 4; ++ni) {
        int j = n0 + wn * 64 + ni * 16 + (lane & 15);
        GA[(size_t)m * 2048 + j] = acc[mi][ni][r] + gx[(size_t)(m & 63) * 2048 + j];
      }
    }
  }
}

// ---- ALL 32 steps, persistent: blocks 0..127 steppers (shfl gate-combine),
// blocks 128..255 convert W_out concurrently. Per-step grid barrier uses RELAXED
// spin polls + ONE release fence before arrive + ONE acquire fence after exit
// (r3's 13us/step came from acquire-per-poll invalidating L2 continuously). -----
__global__ void __launch_bounds__(256) k_steps_p(
    unsigned short* __restrict__ h0, unsigned short* __restrict__ h1,
    float* __restrict__ c, const float* __restrict__ GA,
    const unsigned short* __restrict__ Whb, const int* __restrict__ lens,
    const int* __restrict__ base, unsigned short* __restrict__ Hm,
    int* __restrict__ bar,
    const float* __restrict__ W_out, unsigned short* __restrict__ Wob) {
  int tid = threadIdx.x, bid = blockIdx.x;
  if (bid >= 128) {  // W_out f32->bf16, hidden under the whole step phase
    for (long long i = ((long long)(bid - 128) * 256 + tid) * 8; i < 16384000LL;
         i += 128LL * 256 * 8) {
      float4 v0 = *(const float4*)(W_out + i);
      float4 v1 = *(const float4*)(W_out + i + 4);
      ushort8 o;
      o[0] = f2bf(v0.x); o[1] = f2bf(v0.y); o[2] = f2bf(v0.z); o[3] = f2bf(v0.w);
      o[4] = f2bf(v1.x); o[5] = f2bf(v1.y); o[6] = f2bf(v1.z); o[7] = f2bf(v1.w);
      *(ushort8*)(Wob + i) = o;
    }
    return;
  }
  int lane = tid & 63, w = tid >> 6;
  int lr = lane & 15, lk = lane >> 4;
  int mq = bid & 3, ug = bid >> 2;
  int r0 = mq * 16;
  int gate = lr >> 2, ul = lr & 3;
  int u = ug * 16 + w * 4 + ul;
  int lim = lens[r0];  // group frozen & settled once t > lim

  for (int t = 0; t < 32; ++t) {
    const unsigned short* hin = (t & 1) ? h1 : h0;
    unsigned short* hout = (t & 1) ? h0 : h1;
    if (t <= lim) {
      const float* gab = GA + ((size_t)t * 64 + r0) * 2048 + gate * 512 + u;
      float gv[4];
#pragma unroll
      for (int r = 0; r < 4; ++r) gv[r] = gab[(size_t)(lk * 4 + r) * 2048];
      const unsigned short* Bp = Whb + ((size_t)gate * 512 + u) * 512 + lk * 8;
      const unsigned short* Ap = hin + (size_t)(r0 + lr) * 512 + lk * 8;
      f32x4 acc = (f32x4){0.f, 0.f, 0.f, 0.f};
#pragma unroll
      for (int ks = 0; ks < 16; ++ks) {
        short8 a0 = *(const short8*)(Ap + ks * 32);
        short8 b0 = *(const short8*)(Bp + ks * 32);
        acc = __builtin_amdgcn_mfma_f32_16x16x32_bf16(a0, b0, acc, 0, 0, 0);
      }
#pragma unroll
      for (int r = 0; r < 4; ++r) {
        float v = acc[r] + gv[r];
        float av = (gate == 2) ? tanh_(v) : sigm(v);
        float x4 = __shfl_xor(av, 4);
        float x8 = __shfl_xor(av, 8);
        float x12 = __shfl_xor(av, 12);
        float vi = (gate == 0) ? av : (gate == 1) ? x4 : (gate == 2) ? x8 : x12;
        float vf = (gate == 1) ? av : (gate == 0) ? x4 : (gate == 3) ? x8 : x12;
        float vg = (gate == 2) ? av : (gate == 3) ? x4 : (gate == 0) ? x8 : x12;
        float vo = (gate == 3) ? av : (gate == 2) ? x4 : (gate == 1) ? x8 : x12;
        if (gate == 0) {
          int b = r0 + lk * 4 + r;
          float cold = c[b * 512 + u];
          float cn = vf * cold + vi * vg;
          float hn = vo * tanh_(cn);
          bool act = lens[b] > t;
          if (act) c[b * 512 + u] = cn;
          unsigned short hbv = f2bf(hn);
          hout[b * 512 + u] = act ? hbv : hin[b * 512 + u];
          if (act) Hm[((size_t)(base[b] + t)) * 512 + u] = hbv;
        }
      }
    }
    if (t == 31) break;  // kernel end is the final sync
    __syncthreads();
    if (tid == 0) {
      __threadfence();  // release: flush this block's h/Hm/c stores
      __hip_atomic_fetch_add(&bar[t], 1, __ATOMIC_RELAXED,
                             __HIP_MEMORY_SCOPE_AGENT);
      while (__hip_atomic_load(&bar[t], __ATOMIC_RELAXED,
                               __HIP_MEMORY_SCOPE_AGENT) < 128)
        __builtin_amdgcn_s_sleep(2);
      __threadfence();  // acquire: invalidate local caches once
    }
    __syncthreads();
  }
}

// ---- packed GEMM (blocks 0..3999, 128x128, A+B LDS staged) + zero-fill of
// inactive rows (blocks 4000..4511) ----------------------------------------------
__global__ void __launch_bounds__(256) k_gemm(const unsigned short* __restrict__ Hm,
    const unsigned short* __restrict__ Wb, const float* __restrict__ b_out,
    const int* __restrict__ inv, const int* __restrict__ Pw,
    const int* __restrict__ lens, float* __restrict__ out) {
  int bid = blockIdx.x, tid = threadIdx.x;
  if (bid >= 4000) {  // zero-fill inactive rows, overlapped with gemm
    int idx = bid - 4000;
    float4 z = {0.f, 0.f, 0.f, 0.f};
#pragma unroll
    for (int k = 0; k < 4; ++k) {
      int m = idx * 4 + k;
      int b = m >> 5, t = m & 31;
      if (lens[b] > t) continue;
      float* row = out + (size_t)m * 32000;
      for (int i = tid * 4; i < 32000; i += 1024) *(float4*)(row + i) = z;
    }
    return;
  }
  __shared__ alignas(16) char ldsbuf[32768];
  char* ldsA = ldsbuf;
  char* ldsB = ldsbuf + 16384;
  int P = Pw[0];
  int sb = (bid & 7) * 500 + (bid >> 3);  // XCD chunks, 4000 % 8 == 0
  int mt = sb & 15, nt = sb >> 4;         // mt fast: 16 m-tiles share B slice
  int m0 = mt * 128, n0 = nt * 128;
  if (m0 >= P) return;
  int lane = tid & 63, w = tid >> 6;
  int wm = w >> 1, wn = w & 1;
  f32x4 acc[4][4];
#pragma unroll
  for (int a = 0; a < 4; ++a)
#pragma unroll
    for (int bq = 0; bq < 4; ++bq) acc[a][bq] = (f32x4){0.f, 0.f, 0.f, 0.f};
  const unsigned short* Arow = Hm + (size_t)m0 * 512;
  const unsigned short* Brow = Wb + (size_t)n0 * 512;
  for (int kt = 0; kt < 8; ++kt) {
    int k0 = kt * 64;
    if (kt) __syncthreads();
#pragma unroll
    for (int j = 0; j < 4; ++j) {
      int ci = j * 256 + w * 64 + lane;
      int r = ci >> 3;
      int clog = ((ci & 7) << 4) ^ ((r & 7) << 4);
      int ldst = (j * 256 + w * 64) * 16;
      gll16((const char*)(Arow + (size_t)r * 512 + k0) + clog, ldsA + ldst);
      gll16((const char*)(Brow + (size_t)r * 512 + k0) + clog, ldsB + ldst);
    }
    __syncthreads();
#pragma unroll
    for (int kk = 0; kk < 2; ++kk) {
      short8 af[4], bf[4];
      int cb = kk * 64 + (lane >> 4) * 16;
#pragma unroll
      for (int i = 0; i < 4; ++i) {
        int ar = wm * 64 + i * 16 + (lane & 15);
        af[i] = *(const short8*)(ldsA + ar * 128 + (cb ^ ((ar & 7) << 4)));
        int br = wn * 64 + i * 16 + (lane & 15);
        bf[i] = *(const short8*)(ldsB + br * 128 + (cb ^ ((br & 7) << 4)));
      }
#pragma unroll
      for (int mi = 0; mi < 4; ++mi)
#pragma unroll
        for (int ni = 0; ni < 4; ++ni)
          acc[mi][ni] = __builtin_amdgcn_mfma_f32_16x16x32_bf16(
              af[mi], bf[ni], acc[mi][ni], 0, 0, 0);
    }
  }
#pragma unroll
  for (int mi = 0; mi < 4; ++mi) {
    int pb = m0 + wm * 64 + mi * 16 + ((lane >> 4) << 2);
#pragma unroll
    for (int r = 0; r < 4; ++r) {
      int p = pb + r;
      if (p >= P) continue;
      size_t orow = (size_t)inv[p] * 32000;
#pragma unroll
      for (int ni = 0; ni < 4; ++ni) {
        int n = n0 + wn * 64 + ni * 16 + (lane & 15);
        out[orow + n] = acc[mi][ni][r] + b_out[n];
      }
    }
  }
}

extern "C" void kernel_launch(void* const* d_in, const int* in_sizes, int n_in,
                              void* d_out, int out_size, void* d_ws, size_t ws_size,
                              hipStream_t stream) {
  const float* x     = (const float*)d_in[0];
  const int*   ptar  = (const int*)d_in[1];
  const int*   tlen  = (const int*)d_in[2];
  const float* embed = (const float*)d_in[3];
  const float* W_h0  = (const float*)d_in[4];
  const float* b_h0  = (const float*)d_in[5];
  const float* W_c0  = (const float*)d_in[6];
  const float* b_c0  = (const float*)d_in[7];
  const float* W_ih  = (const float*)d_in[8];
  const float* W_hh  = (const float*)d_in[9];
  const float* b_ih  = (const float*)d_in[10];
  const float* b_hh  = (const float*)d_in[11];
  const float* W_out = (const float*)d_in[12];
  const float* b_out = (const float*)d_in[13];
  float* out = (float*)d_out;

  char* ws = (char*)d_ws;
  size_t off = 0;
  auto alloc = [&](size_t bytes) {
    void* p = ws + off;
    off += (bytes + 255) & ~(size_t)255;
    return p;
  };
  unsigned short* Wob = (unsigned short*)alloc(32000ull * 512 * 2);
  unsigned short* Hm  = (unsigned short*)alloc(2048ull * 512 * 2);
  unsigned short* h0b = (unsigned short*)alloc(64 * 512 * 2);
  unsigned short* h1b = (unsigned short*)alloc(64 * 512 * 2);
  float* cbuf = (float*)alloc(64 * 512 * 4);
  float* gx   = (float*)alloc(64 * 2048 * 4);
  int* sidx = (int*)alloc(64 * 4);
  int* lens = (int*)alloc(64 * 4);
  int* base = (int*)alloc(64 * 4);
  int* inv  = (int*)alloc(2048 * 4);
  int* Pw   = (int*)alloc(4);
  int* tok  = (int*)alloc(2048 * 4);
  int* bar  = (int*)alloc(32 * 4);

  // scratch in d_out's prediction region (all dead before gemm/zf overwrite)
  float* GA = out;                                             // 2048*2048 f32
  unsigned short* Wpro  = (unsigned short*)(out + 4194304);    // 3072*512 bf16
  unsigned short* Wihb2 = (unsigned short*)(out + 4980736);    // 2048*256 bf16
  unsigned short* Whb   = (unsigned short*)(out + 5242880);    // 2048*512 bf16
  unsigned short* Eb    = (unsigned short*)(out + 5767168);    // 2048*256 bf16
  unsigned short* xsb   = (unsigned short*)(out + 6029312);    // 64*512 bf16
  float* tail = out + 65536000;                                // sorted_indices

  k_pre<<<1537, 256, 0, stream>>>(x, ptar, tlen, W_h0, W_c0, W_ih, W_hh,
                                  sidx, lens, base, inv, Pw, tok, xsb, tail,
                                  Wpro, Wihb2, Whb, bar);
  k_mid<<<304, 256, 0, stream>>>(xsb, Wpro, b_h0, b_c0, b_ih, b_hh, h0b, cbuf,
                                 gx, tok, embed, Eb);
  k_ga2<<<256, 256, 0, stream>>>(Eb, Wihb2, gx, GA);
  k_steps_p<<<256, 256, 0, stream>>>(h0b, h1b, cbuf, GA, Whb, lens, base, Hm,
                                     bar, W_out, Wob);
  k_gemm<<<4512, 256, 0, stream>>>(Hm, Wob, b_out, inv, Pw, lens, out);
  (void)in_sizes; (void)n_in; (void)out_size; (void)ws_size;
}

// Round 10
// 433.289 us; speedup vs baseline: 1.5089x; 1.5089x over previous
//
#include <hip/hip_runtime.h>

typedef __attribute__((ext_vector_type(8))) short short8;
typedef __attribute__((ext_vector_type(8))) unsigned short ushort8;
typedef __attribute__((ext_vector_type(4))) float f32x4;

#define DEV __device__ __forceinline__

DEV unsigned short f2bf(float f) {
  unsigned int u = __float_as_uint(f);
  u += 0x7fffu + ((u >> 16) & 1u);
  return (unsigned short)(u >> 16);
}
DEV float sigm(float x) { return 1.f / (1.f + __expf(-x)); }
DEV float tanh_(float x) { return 1.f - 2.f / (1.f + __expf(2.f * x)); }

typedef __attribute__((address_space(1))) const void* as1cv;
typedef __attribute__((address_space(3))) void* as3v;
DEV void gll16(const void* g, void* l) {
  __builtin_amdgcn_global_load_lds((as1cv)g, (as3v)l, 16, 0, 0);
}

// ---- k_pre: block 0 = sort + gathers + packing meta (+xsb); blocks 1..1536 =
// weight conversions Wpro(3072x512) | Wihb2(2048x256) | Whb(2048x512) ------------
__global__ void __launch_bounds__(256) k_pre(const float* __restrict__ x,
    const int* __restrict__ ptar, const int* __restrict__ tlen,
    const float* __restrict__ W_h0, const float* __restrict__ W_c0,
    const float* __restrict__ W_ih, const float* __restrict__ W_hh,
    int* __restrict__ sidx, int* __restrict__ lens, int* __restrict__ base,
    int* __restrict__ inv, int* __restrict__ Pw, int* __restrict__ tok,
    unsigned short* __restrict__ xsb, float* __restrict__ tail,
    unsigned short* __restrict__ Wpro, unsigned short* __restrict__ Wihb2,
    unsigned short* __restrict__ Whb) {
  int bid = blockIdx.x, tid = threadIdx.x;
  if (bid > 0) {  // weight conversions (independent of sort)
    long long g = (long long)(bid - 1) * 2048 + tid * 8;
    const float* src;
    unsigned short* dst;
    if (g < 262144) {                       // W_h0 -> Wpro[0:512]
      src = W_h0 + g; dst = Wpro + g;
    } else if (g < 524288) {                // W_c0 -> Wpro[512:1024]
      long long l = g - 262144; src = W_c0 + l; dst = Wpro + 262144 + l;
    } else if (g < 1572864) {               // W_ih[:, :512] -> Wpro[1024:3072]
      long long l = g - 524288;
      long long r = l >> 9, c = l & 511;
      src = W_ih + r * 768 + c; dst = Wpro + 524288 + l;
    } else if (g < 2097152) {               // W_ih[:, 512:768] -> Wihb2
      long long l = g - 1572864;
      long long r = l >> 8, c = l & 255;
      src = W_ih + r * 768 + 512 + c; dst = Wihb2 + l;
    } else {                                // W_hh -> Whb
      long long l = g - 2097152; src = W_hh + l; dst = Whb + l;
    }
    float4 v0 = *(const float4*)src, v1 = *(const float4*)(src + 4);
    ushort8 o;
    o[0] = f2bf(v0.x); o[1] = f2bf(v0.y); o[2] = f2bf(v0.z); o[3] = f2bf(v0.w);
    o[4] = f2bf(v1.x); o[5] = f2bf(v1.y); o[6] = f2bf(v1.z); o[7] = f2bf(v1.w);
    *(ushort8*)dst = o;
    return;
  }
  __shared__ int ss[64], ls[64], bs[64];
  if (tid < 64) {
    int li = tlen[tid];
    int rank = 0;
    for (int j = 0; j < 64; ++j) {
      int lj = tlen[j];
      rank += (lj > li || (lj == li && j < tid)) ? 1 : 0;
    }
    ss[rank] = tid;
  }
  __syncthreads();
  if (tid < 64) {
    int src = ss[tid];
    sidx[tid] = src;
    int l = tlen[src] - 1;
    ls[tid] = l;
    lens[tid] = l;
    tail[tid] = (float)src;
  }
  __syncthreads();
  if (tid == 0) {
    int s = 0;
    for (int b = 0; b < 64; ++b) { bs[b] = s; base[b] = s; s += ls[b]; }
    Pw[0] = s;
  }
  __syncthreads();
  for (int idx = tid; idx < 2048; idx += 256) {
    int b = idx >> 5, t = idx & 31;
    if (t < ls[b]) inv[bs[b] + t] = idx;
  }
  for (int idx = tid; idx < 32 * 64; idx += 256) {
    int t = idx >> 6, b = idx & 63;
    tok[idx] = ptar[ss[b] * 33 + t];
  }
  for (int idx = tid; idx < 64 * 512; idx += 256) {
    int b = idx >> 9;
    xsb[idx] = f2bf(x[ss[b] * 512 + (idx & 511)]);
  }
}

// ---- k_mid: blocks 0..47 = prologue GEMM (h0/c0/gx); blocks 48..303 = embedding
// gather -> bf16 Eb[2048][256] ----------------------------------------------------
__global__ void __launch_bounds__(256) k_mid(const unsigned short* __restrict__ xsb,
    const unsigned short* __restrict__ Wpro, const float* __restrict__ b_h0,
    const float* __restrict__ b_c0, const float* __restrict__ b_ih,
    const float* __restrict__ b_hh, unsigned short* __restrict__ h0b,
    float* __restrict__ c, float* __restrict__ gx,
    const int* __restrict__ tok, const float* __restrict__ embed,
    unsigned short* __restrict__ Eb) {
  int bid = blockIdx.x, tid = threadIdx.x;
  if (bid >= 48) {  // embedding gather
    int gid = (bid - 48) * 256 + tid;
    int row = gid >> 5, c8 = (gid & 31) * 8;
    const float* src = embed + (size_t)tok[row] * 256 + c8;
    float4 v0 = *(const float4*)src, v1 = *(const float4*)(src + 4);
    ushort8 o;
    o[0] = f2bf(v0.x); o[1] = f2bf(v0.y); o[2] = f2bf(v0.z); o[3] = f2bf(v0.w);
    o[4] = f2bf(v1.x); o[5] = f2bf(v1.y); o[6] = f2bf(v1.z); o[7] = f2bf(v1.w);
    *(ushort8*)(Eb + (size_t)row * 256 + c8) = o;
    return;
  }
  int lane = tid & 63, w = tid >> 6;
  int n0 = bid * 64 + w * 16;
  int lr = lane & 15, lk = lane >> 4;
  f32x4 acc[4];
#pragma unroll
  for (int i = 0; i < 4; ++i) acc[i] = (f32x4){0.f, 0.f, 0.f, 0.f};
  const unsigned short* B = Wpro + (size_t)(n0 + lr) * 512 + lk * 8;
  const unsigned short* A = xsb + (size_t)lr * 512 + lk * 8;
#pragma unroll
  for (int ks = 0; ks < 16; ++ks) {
    short8 bfr = *(const short8*)(B + ks * 32);
#pragma unroll
    for (int mi = 0; mi < 4; ++mi) {
      short8 af = *(const short8*)(A + mi * 16 * 512 + ks * 32);
      acc[mi] = __builtin_amdgcn_mfma_f32_16x16x32_bf16(af, bfr, acc[mi], 0, 0, 0);
    }
  }
  int n = n0 + lr;
#pragma unroll
  for (int mi = 0; mi < 4; ++mi)
#pragma unroll
    for (int r = 0; r < 4; ++r) {
      int b = mi * 16 + lk * 4 + r;
      float v = acc[mi][r];
      if (n < 512) {
        h0b[b * 512 + n] = f2bf(v + b_h0[n]);
      } else if (n < 1024) {
        int u = n - 512;
        c[b * 512 + u] = v + b_c0[u];
      } else {
        int j = n - 1024;
        gx[(size_t)b * 2048 + j] = v + b_ih[j] + b_hh[j];
      }
    }
}

// ---- GA = Eb @ Wihb2^T + gx (blocks 0..255); blocks 256..505: W_out->bf16 ------
__global__ void __launch_bounds__(256) k_ga2(const unsigned short* __restrict__ Eb,
    const unsigned short* __restrict__ Wb2, const float* __restrict__ gx,
    float* __restrict__ GA, const float* __restrict__ W_out,
    unsigned short* __restrict__ Wob) {
  int bid = blockIdx.x, tid = threadIdx.x;
  if (bid >= 256) {  // W_out f32->bf16: 250 blocks x 65536 elems (r4 placement)
    long long basei = (long long)(bid - 256) * 65536;
#pragma unroll 4
    for (int it = 0; it < 32; ++it) {
      long long i = basei + (long long)it * 2048 + tid * 8;
      float4 v0 = *(const float4*)(W_out + i);
      float4 v1 = *(const float4*)(W_out + i + 4);
      ushort8 o;
      o[0] = f2bf(v0.x); o[1] = f2bf(v0.y); o[2] = f2bf(v0.z); o[3] = f2bf(v0.w);
      o[4] = f2bf(v1.x); o[5] = f2bf(v1.y); o[6] = f2bf(v1.z); o[7] = f2bf(v1.w);
      *(ushort8*)(Wob + i) = o;
    }
    return;
  }
  __shared__ alignas(16) char ldsbuf[32768];
  char* ldsA = ldsbuf;
  char* ldsB = ldsbuf + 16384;
  int mt = bid & 15, nt = bid >> 4;
  int m0 = mt * 128, n0 = nt * 128;
  int lane = tid & 63, w = tid >> 6;
  int wm = w >> 1, wn = w & 1;
  f32x4 acc[4][4];
#pragma unroll
  for (int a = 0; a < 4; ++a)
#pragma unroll
    for (int bq = 0; bq < 4; ++bq) acc[a][bq] = (f32x4){0.f, 0.f, 0.f, 0.f};
  const unsigned short* Arow = Eb + (size_t)m0 * 256;
  const unsigned short* Brow = Wb2 + (size_t)n0 * 256;
  for (int kt = 0; kt < 4; ++kt) {
    int k0 = kt * 64;
    if (kt) __syncthreads();
#pragma unroll
    for (int j = 0; j < 4; ++j) {
      int ci = j * 256 + w * 64 + lane;
      int r = ci >> 3;
      int clog = ((ci & 7) << 4) ^ ((r & 7) << 4);
      int ldst = (j * 256 + w * 64) * 16;
      gll16((const char*)(Arow + (size_t)r * 256 + k0) + clog, ldsA + ldst);
      gll16((const char*)(Brow + (size_t)r * 256 + k0) + clog, ldsB + ldst);
    }
    __syncthreads();
#pragma unroll
    for (int kk = 0; kk < 2; ++kk) {
      short8 af[4], bf[4];
      int cb = kk * 64 + (lane >> 4) * 16;
#pragma unroll
      for (int i = 0; i < 4; ++i) {
        int ar = wm * 64 + i * 16 + (lane & 15);
        af[i] = *(const short8*)(ldsA + ar * 128 + (cb ^ ((ar & 7) << 4)));
        int br = wn * 64 + i * 16 + (lane & 15);
        bf[i] = *(const short8*)(ldsB + br * 128 + (cb ^ ((br & 7) << 4)));
      }
#pragma unroll
      for (int mi = 0; mi < 4; ++mi)
#pragma unroll
        for (int ni = 0; ni < 4; ++ni)
          acc[mi][ni] = __builtin_amdgcn_mfma_f32_16x16x32_bf16(
              af[mi], bf[ni], acc[mi][ni], 0, 0, 0);
    }
  }
#pragma unroll
  for (int mi = 0; mi < 4; ++mi) {
    int mb = m0 + wm * 64 + mi * 16 + ((lane >> 4) << 2);
#pragma unroll
    for (int r = 0; r < 4; ++r) {
      int m = mb + r;
#pragma unroll
      for (int ni = 0; ni < 4; ++ni) {
        int j = n0 + wn * 64 + ni * 16 + (lane & 15);
        GA[(size_t)m * 2048 + j] = acc[mi][ni][r] + gx[(size_t)(m & 63) * 2048 + j];
      }
    }
  }
}

// ---- one LSTM step, shfl gate-combine, full register preload -------------------
// launch_bounds(256,1): VGPR cap lifted (occupancy is 0.5 waves/SIMD regardless)
// so all 32 fragment loads + 4 GA loads are in flight at once (one L2 round trip
// instead of ~16 serialized; r9 showed VGPR_Count=52 strangled the pipeline).
__global__ void __launch_bounds__(256, 1) k_step4(
    const unsigned short* __restrict__ hin, unsigned short* __restrict__ hout,
    float* __restrict__ c, const float* __restrict__ GA,
    const unsigned short* __restrict__ Whb, const int* __restrict__ lens,
    const int* __restrict__ base, unsigned short* __restrict__ Hm, int t) {
  int tid = threadIdx.x, bid = blockIdx.x;
  int mq = bid & 3, ug = bid >> 2;
  int r0 = mq * 16;
  if (t > lens[r0]) return;  // whole 16-row group frozen & settled
  int lane = tid & 63, w = tid >> 6;
  int lr = lane & 15, lk = lane >> 4;
  int gate = lr >> 2, ul = lr & 3;
  int u = ug * 16 + w * 4 + ul;

  const float* gab = GA + ((size_t)t * 64 + r0) * 2048 + gate * 512 + u;
  float gv[4];
#pragma unroll
  for (int r = 0; r < 4; ++r) gv[r] = gab[(size_t)(lk * 4 + r) * 2048];

  const unsigned short* Bp = Whb + ((size_t)gate * 512 + u) * 512 + lk * 8;
  const unsigned short* Ap = hin + (size_t)(r0 + lr) * 512 + lk * 8;
  short8 bfr[16], afr[16];
#pragma unroll
  for (int ks = 0; ks < 16; ++ks) bfr[ks] = *(const short8*)(Bp + ks * 32);
#pragma unroll
  for (int ks = 0; ks < 16; ++ks) afr[ks] = *(const short8*)(Ap + ks * 32);
  f32x4 acc = (f32x4){0.f, 0.f, 0.f, 0.f};
#pragma unroll
  for (int ks = 0; ks < 16; ++ks)
    acc = __builtin_amdgcn_mfma_f32_16x16x32_bf16(afr[ks], bfr[ks], acc, 0, 0, 0);

#pragma unroll
  for (int r = 0; r < 4; ++r) {
    float v = acc[r] + gv[r];
    float av = (gate == 2) ? tanh_(v) : sigm(v);  // i,f,o: sigmoid; g: tanh
    float x4 = __shfl_xor(av, 4);
    float x8 = __shfl_xor(av, 8);
    float x12 = __shfl_xor(av, 12);
    float vi = (gate == 0) ? av : (gate == 1) ? x4 : (gate == 2) ? x8 : x12;
    float vf = (gate == 1) ? av : (gate == 0) ? x4 : (gate == 3) ? x8 : x12;
    float vg = (gate == 2) ? av : (gate == 3) ? x4 : (gate == 0) ? x8 : x12;
    float vo = (gate == 3) ? av : (gate == 2) ? x4 : (gate == 1) ? x8 : x12;
    if (gate == 0) {
      int b = r0 + lk * 4 + r;
      float cold = c[b * 512 + u];
      float cn = vf * cold + vi * vg;
      float hn = vo * tanh_(cn);
      bool act = lens[b] > t;
      if (act) c[b * 512 + u] = cn;
      unsigned short hbv = f2bf(hn);
      hout[b * 512 + u] = act ? hbv : hin[b * 512 + u];
      if (act) Hm[((size_t)(base[b] + t)) * 512 + u] = hbv;
    }
  }
}

// ---- packed GEMM, 512 threads, 128x256 tile (blocks 0..1999) + zero-fill of
// inactive rows (blocks 2000..2511) — r4's measured-best gemm, zf fused ----------
__global__ void __launch_bounds__(512) k_gemm(const unsigned short* __restrict__ Hm,
    const unsigned short* __restrict__ Wb, const float* __restrict__ b_out,
    const int* __restrict__ inv, const int* __restrict__ Pw,
    const int* __restrict__ lens, float* __restrict__ out) {
  int bid = blockIdx.x, tid = threadIdx.x;
  if (bid >= 2000) {  // zero-fill inactive rows, overlapped with gemm
    int idx = bid - 2000;
    float4 z = {0.f, 0.f, 0.f, 0.f};
#pragma unroll
    for (int k = 0; k < 4; ++k) {
      int m = idx * 4 + k;
      int b = m >> 5, t = m & 31;
      if (lens[b] > t) continue;
      float* row = out + (size_t)m * 32000;
      for (int i = tid * 4; i < 32000; i += 2048) *(float4*)(row + i) = z;
    }
    return;
  }
  __shared__ alignas(16) char ldsbuf[49152];  // A 16KB | B 32KB
  char* ldsA = ldsbuf;
  char* ldsB = ldsbuf + 16384;
  int P = Pw[0];
  int sb = (bid & 7) * 250 + (bid >> 3);  // XCD chunks, 2000 % 8 == 0
  int mt = sb % 16, nt = sb / 16;         // mt fast: 16 m-tiles share B slice
  int m0 = mt * 128, n0 = nt * 256;
  if (m0 >= P) return;
  int lane = tid & 63, w = tid >> 6;
  int wm = w >> 2, wn = w & 3;  // 2x4 waves, 64x64 out per wave
  f32x4 acc[4][4];
#pragma unroll
  for (int a = 0; a < 4; ++a)
#pragma unroll
    for (int bq = 0; bq < 4; ++bq) acc[a][bq] = (f32x4){0.f, 0.f, 0.f, 0.f};
  const unsigned short* Arow = Hm + (size_t)m0 * 512;
  const unsigned short* Brow = Wb + (size_t)n0 * 512;
  for (int kt = 0; kt < 8; ++kt) {
    int k0 = kt * 64;
    if (kt) __syncthreads();
#pragma unroll
    for (int j = 0; j < 2; ++j) {  // A: 1024 16B chunks
      int ci = j * 512 + tid;
      int r = ci >> 3;
      int clog = ((ci & 7) << 4) ^ ((r & 7) << 4);
      gll16((const char*)(Arow + (size_t)r * 512 + k0) + clog, ldsA + ci * 16);
    }
#pragma unroll
    for (int j = 0; j < 4; ++j) {  // B: 2048 16B chunks
      int ci = j * 512 + tid;
      int r = ci >> 3;
      int clog = ((ci & 7) << 4) ^ ((r & 7) << 4);
      gll16((const char*)(Brow + (size_t)r * 512 + k0) + clog, ldsB + ci * 16);
    }
    __syncthreads();
#pragma unroll
    for (int kk = 0; kk < 2; ++kk) {
      short8 af[4], bf[4];
      int cb = kk * 64 + (lane >> 4) * 16;
#pragma unroll
      for (int i = 0; i < 4; ++i) {
        int ar = wm * 64 + i * 16 + (lane & 15);
        af[i] = *(const short8*)(ldsA + ar * 128 + (cb ^ ((ar & 7) << 4)));
        int br = wn * 64 + i * 16 + (lane & 15);
        bf[i] = *(const short8*)(ldsB + br * 128 + (cb ^ ((br & 7) << 4)));
      }
#pragma unroll
      for (int mi = 0; mi < 4; ++mi)
#pragma unroll
        for (int ni = 0; ni < 4; ++ni)
          acc[mi][ni] = __builtin_amdgcn_mfma_f32_16x16x32_bf16(
              af[mi], bf[ni], acc[mi][ni], 0, 0, 0);
    }
  }
#pragma unroll
  for (int mi = 0; mi < 4; ++mi) {
    int pb = m0 + wm * 64 + mi * 16 + ((lane >> 4) << 2);
#pragma unroll
    for (int r = 0; r < 4; ++r) {
      int p = pb + r;
      if (p >= P) continue;
      size_t orow = (size_t)inv[p] * 32000;
#pragma unroll
      for (int ni = 0; ni < 4; ++ni) {
        int n = n0 + wn * 64 + ni * 16 + (lane & 15);
        out[orow + n] = acc[mi][ni][r] + b_out[n];
      }
    }
  }
}

extern "C" void kernel_launch(void* const* d_in, const int* in_sizes, int n_in,
                              void* d_out, int out_size, void* d_ws, size_t ws_size,
                              hipStream_t stream) {
  const float* x     = (const float*)d_in[0];
  const int*   ptar  = (const int*)d_in[1];
  const int*   tlen  = (const int*)d_in[2];
  const float* embed = (const float*)d_in[3];
  const float* W_h0  = (const float*)d_in[4];
  const float* b_h0  = (const float*)d_in[5];
  const float* W_c0  = (const float*)d_in[6];
  const float* b_c0  = (const float*)d_in[7];
  const float* W_ih  = (const float*)d_in[8];
  const float* W_hh  = (const float*)d_in[9];
  const float* b_ih  = (const float*)d_in[10];
  const float* b_hh  = (const float*)d_in[11];
  const float* W_out = (const float*)d_in[12];
  const float* b_out = (const float*)d_in[13];
  float* out = (float*)d_out;

  char* ws = (char*)d_ws;
  size_t off = 0;
  auto alloc = [&](size_t bytes) {
    void* p = ws + off;
    off += (bytes + 255) & ~(size_t)255;
    return p;
  };
  unsigned short* Wob = (unsigned short*)alloc(32000ull * 512 * 2);
  unsigned short* Hm  = (unsigned short*)alloc(2048ull * 512 * 2);
  unsigned short* h0b = (unsigned short*)alloc(64 * 512 * 2);
  unsigned short* h1b = (unsigned short*)alloc(64 * 512 * 2);
  float* cbuf = (float*)alloc(64 * 512 * 4);
  float* gx   = (float*)alloc(64 * 2048 * 4);
  int* sidx = (int*)alloc(64 * 4);
  int* lens = (int*)alloc(64 * 4);
  int* base = (int*)alloc(64 * 4);
  int* inv  = (int*)alloc(2048 * 4);
  int* Pw   = (int*)alloc(4);
  int* tok  = (int*)alloc(2048 * 4);

  // scratch in d_out's prediction region (all dead before gemm/zf overwrite)
  float* GA = out;                                             // 2048*2048 f32
  unsigned short* Wpro  = (unsigned short*)(out + 4194304);    // 3072*512 bf16
  unsigned short* Wihb2 = (unsigned short*)(out + 4980736);    // 2048*256 bf16
  unsigned short* Whb   = (unsigned short*)(out + 5242880);    // 2048*512 bf16
  unsigned short* Eb    = (unsigned short*)(out + 5767168);    // 2048*256 bf16
  unsigned short* xsb   = (unsigned short*)(out + 6029312);    // 64*512 bf16
  float* tail = out + 65536000;                                // sorted_indices

  k_pre<<<1537, 256, 0, stream>>>(x, ptar, tlen, W_h0, W_c0, W_ih, W_hh,
                                  sidx, lens, base, inv, Pw, tok, xsb, tail,
                                  Wpro, Wihb2, Whb);
  k_mid<<<304, 256, 0, stream>>>(xsb, Wpro, b_h0, b_c0, b_ih, b_hh, h0b, cbuf,
                                 gx, tok, embed, Eb);
  k_ga2<<<506, 256, 0, stream>>>(Eb, Wihb2, gx, GA, W_out, Wob);

  unsigned short* hb[2] = {h0b, h1b};
  for (int t = 0; t < 32; ++t)
    k_step4<<<128, 256, 0, stream>>>(hb[t & 1], hb[(t + 1) & 1], cbuf, GA, Whb,
                                     lens, base, Hm, t);

  k_gemm<<<2512, 512, 0, stream>>>(Hm, Wob, b_out, inv, Pw, lens, out);
  (void)in_sizes; (void)n_in; (void)out_size; (void)ws_size;
}

// Round 11
// 380.131 us; speedup vs baseline: 1.7199x; 1.1398x over previous
//
#include <hip/hip_runtime.h>

typedef __attribute__((ext_vector_type(8))) short short8;
typedef __attribute__((ext_vector_type(8))) unsigned short ushort8;
typedef __attribute__((ext_vector_type(4))) float f32x4;

#define DEV __device__ __forceinline__

DEV unsigned short f2bf(float f) {
  unsigned int u = __float_as_uint(f);
  u += 0x7fffu + ((u >> 16) & 1u);
  return (unsigned short)(u >> 16);
}
DEV float sigm(float x) { return 1.f / (1.f + __expf(-x)); }
DEV float tanh_(float x) { return 1.f - 2.f / (1.f + __expf(2.f * x)); }

typedef __attribute__((address_space(1))) const void* as1cv;
typedef __attribute__((address_space(3))) void* as3v;
DEV void gll16(const void* g, void* l) {
  __builtin_amdgcn_global_load_lds((as1cv)g, (as3v)l, 16, 0, 0);
}

// LLC-coherent h passing: stores write through L1/L2 to Infinity Cache; loads
// bypass (possibly stale) L1/L2 and read the LLC. Weights/GA stay L2-cached.
DEV void st2_llc(unsigned short* p, unsigned short v) {
  unsigned int vv = v;
  asm volatile("global_store_short %0, %1, off sc0 sc1" :: "v"(p), "v"(vv)
               : "memory");
}
DEV short8 ld16_llc(const unsigned short* p) {
  short8 r;
  asm volatile("global_load_dwordx4 %0, %1, off sc0 sc1" : "=&v"(r) : "v"(p)
               : "memory");
  return r;
}

// ---- k_pre: block 0 = sort + gathers + packing meta + bar-zero; blocks 1.. =
// weight conversions Wpro(3072x512) | Wihb2(2048x256) | Whb(2048x512) ------------
__global__ void __launch_bounds__(256) k_pre(const float* __restrict__ x,
    const int* __restrict__ ptar, const int* __restrict__ tlen,
    const float* __restrict__ W_h0, const float* __restrict__ W_c0,
    const float* __restrict__ W_ih, const float* __restrict__ W_hh,
    int* __restrict__ sidx, int* __restrict__ lens, int* __restrict__ base,
    int* __restrict__ inv, int* __restrict__ Pw, int* __restrict__ tok,
    unsigned short* __restrict__ xsb, float* __restrict__ tail,
    unsigned short* __restrict__ Wpro, unsigned short* __restrict__ Wihb2,
    unsigned short* __restrict__ Whb, int* __restrict__ bar) {
  int bid = blockIdx.x, tid = threadIdx.x;
  if (bid > 0) {
    long long g = (long long)(bid - 1) * 2048 + tid * 8;
    const float* src;
    unsigned short* dst;
    if (g < 262144) {
      src = W_h0 + g; dst = Wpro + g;
    } else if (g < 524288) {
      long long l = g - 262144; src = W_c0 + l; dst = Wpro + 262144 + l;
    } else if (g < 1572864) {
      long long l = g - 524288;
      long long r = l >> 9, c = l & 511;
      src = W_ih + r * 768 + c; dst = Wpro + 524288 + l;
    } else if (g < 2097152) {
      long long l = g - 1572864;
      long long r = l >> 8, c = l & 255;
      src = W_ih + r * 768 + 512 + c; dst = Wihb2 + l;
    } else {
      long long l = g - 2097152; src = W_hh + l; dst = Whb + l;
    }
    float4 v0 = *(const float4*)src, v1 = *(const float4*)(src + 4);
    ushort8 o;
    o[0] = f2bf(v0.x); o[1] = f2bf(v0.y); o[2] = f2bf(v0.z); o[3] = f2bf(v0.w);
    o[4] = f2bf(v1.x); o[5] = f2bf(v1.y); o[6] = f2bf(v1.z); o[7] = f2bf(v1.w);
    *(ushort8*)dst = o;
    return;
  }
  __shared__ int ss[64], ls[64], bs[64];
  for (int idx = tid; idx < 2048; idx += 256) bar[idx] = 0;  // 4 grp x 32 t x 16
  if (tid < 64) {
    int li = tlen[tid];
    int rank = 0;
    for (int j = 0; j < 64; ++j) {
      int lj = tlen[j];
      rank += (lj > li || (lj == li && j < tid)) ? 1 : 0;
    }
    ss[rank] = tid;
  }
  __syncthreads();
  if (tid < 64) {
    int src = ss[tid];
    sidx[tid] = src;
    int l = tlen[src] - 1;
    ls[tid] = l;
    lens[tid] = l;
    tail[tid] = (float)src;
  }
  __syncthreads();
  if (tid == 0) {
    int s = 0;
    for (int b = 0; b < 64; ++b) { bs[b] = s; base[b] = s; s += ls[b]; }
    Pw[0] = s;
  }
  __syncthreads();
  for (int idx = tid; idx < 2048; idx += 256) {
    int b = idx >> 5, t = idx & 31;
    if (t < ls[b]) inv[bs[b] + t] = idx;
  }
  for (int idx = tid; idx < 32 * 64; idx += 256) {
    int t = idx >> 6, b = idx & 63;
    tok[idx] = ptar[ss[b] * 33 + t];
  }
  for (int idx = tid; idx < 64 * 512; idx += 256) {
    int b = idx >> 9;
    xsb[idx] = f2bf(x[ss[b] * 512 + (idx & 511)]);
  }
}

// ---- k_mid: blocks 0..47 = prologue GEMM (h0/c0/gx); blocks 48..303 = embedding
__global__ void __launch_bounds__(256) k_mid(const unsigned short* __restrict__ xsb,
    const unsigned short* __restrict__ Wpro, const float* __restrict__ b_h0,
    const float* __restrict__ b_c0, const float* __restrict__ b_ih,
    const float* __restrict__ b_hh, unsigned short* __restrict__ h0b,
    float* __restrict__ c, float* __restrict__ gx,
    const int* __restrict__ tok, const float* __restrict__ embed,
    unsigned short* __restrict__ Eb) {
  int bid = blockIdx.x, tid = threadIdx.x;
  if (bid >= 48) {
    int gid = (bid - 48) * 256 + tid;
    int row = gid >> 5, c8 = (gid & 31) * 8;
    const float* src = embed + (size_t)tok[row] * 256 + c8;
    float4 v0 = *(const float4*)src, v1 = *(const float4*)(src + 4);
    ushort8 o;
    o[0] = f2bf(v0.x); o[1] = f2bf(v0.y); o[2] = f2bf(v0.z); o[3] = f2bf(v0.w);
    o[4] = f2bf(v1.x); o[5] = f2bf(v1.y); o[6] = f2bf(v1.z); o[7] = f2bf(v1.w);
    *(ushort8*)(Eb + (size_t)row * 256 + c8) = o;
    return;
  }
  int lane = tid & 63, w = tid >> 6;
  int n0 = bid * 64 + w * 16;
  int lr = lane & 15, lk = lane >> 4;
  f32x4 acc[4];
#pragma unroll
  for (int i = 0; i < 4; ++i) acc[i] = (f32x4){0.f, 0.f, 0.f, 0.f};
  const unsigned short* B = Wpro + (size_t)(n0 + lr) * 512 + lk * 8;
  const unsigned short* A = xsb + (size_t)lr * 512 + lk * 8;
#pragma unroll
  for (int ks = 0; ks < 16; ++ks) {
    short8 bfr = *(const short8*)(B + ks * 32);
#pragma unroll
    for (int mi = 0; mi < 4; ++mi) {
      short8 af = *(const short8*)(A + mi * 16 * 512 + ks * 32);
      acc[mi] = __builtin_amdgcn_mfma_f32_16x16x32_bf16(af, bfr, acc[mi], 0, 0, 0);
    }
  }
  int n = n0 + lr;
#pragma unroll
  for (int mi = 0; mi < 4; ++mi)
#pragma unroll
    for (int r = 0; r < 4; ++r) {
      int b = mi * 16 + lk * 4 + r;
      float v = acc[mi][r];
      if (n < 512) {
        h0b[b * 512 + n] = f2bf(v + b_h0[n]);
      } else if (n < 1024) {
        int u = n - 512;
        c[b * 512 + u] = v + b_c0[u];
      } else {
        int j = n - 1024;
        gx[(size_t)b * 2048 + j] = v + b_ih[j] + b_hh[j];
      }
    }
}

// ---- GA[m][j] = Eb[m].Wihb2[j] + gx[m&63][j]   (2048x2048, K=256) --------------
__global__ void __launch_bounds__(256) k_ga2(const unsigned short* __restrict__ Eb,
    const unsigned short* __restrict__ Wb2, const float* __restrict__ gx,
    float* __restrict__ GA) {
  __shared__ alignas(16) char ldsbuf[32768];
  char* ldsA = ldsbuf;
  char* ldsB = ldsbuf + 16384;
  int bid = blockIdx.x, tid = threadIdx.x;
  int mt = bid & 15, nt = bid >> 4;
  int m0 = mt * 128, n0 = nt * 128;
  int lane = tid & 63, w = tid >> 6;
  int wm = w >> 1, wn = w & 1;
  f32x4 acc[4][4];
#pragma unroll
  for (int a = 0; a < 4; ++a)
#pragma unroll
    for (int bq = 0; bq < 4; ++bq) acc[a][bq] = (f32x4){0.f, 0.f, 0.f, 0.f};
  const unsigned short* Arow = Eb + (size_t)m0 * 256;
  const unsigned short* Brow = Wb2 + (size_t)n0 * 256;
  for (int kt = 0; kt < 4; ++kt) {
    int k0 = kt * 64;
    if (kt) __syncthreads();
#pragma unroll
    for (int j = 0; j < 4; ++j) {
      int ci = j * 256 + w * 64 + lane;
      int r = ci >> 3;
      int clog = ((ci & 7) << 4) ^ ((r & 7) << 4);
      int ldst = (j * 256 + w * 64) * 16;
      gll16((const char*)(Arow + (size_t)r * 256 + k0) + clog, ldsA + ldst);
      gll16((const char*)(Brow + (size_t)r * 256 + k0) + clog, ldsB + ldst);
    }
    __syncthreads();
#pragma unroll
    for (int kk = 0; kk < 2; ++kk) {
      short8 af[4], bf[4];
      int cb = kk * 64 + (lane >> 4) * 16;
#pragma unroll
      for (int i = 0; i < 4; ++i) {
        int ar = wm * 64 + i * 16 + (lane & 15);
        af[i] = *(const short8*)(ldsA + ar * 128 + (cb ^ ((ar & 7) << 4)));
        int br = wn * 64 + i * 16 + (lane & 15);
        bf[i] = *(const short8*)(ldsB + br * 128 + (cb ^ ((br & 7) << 4)));
      }
#pragma unroll
      for (int mi = 0; mi < 4; ++mi)
#pragma unroll
        for (int ni = 0; ni < 4; ++ni)
          acc[mi][ni] = __builtin_amdgcn_mfma_f32_16x16x32_bf16(
              af[mi], bf[ni], acc[mi][ni], 0, 0, 0);
    }
  }
#pragma unroll
  for (int mi = 0; mi < 4; ++mi) {
    int mb = m0 + wm * 64 + mi * 16 + ((lane >> 4) << 2);
#pragma unroll
    for (int r = 0; r < 4; ++r) {
      int m = mb + r;
#pragma unroll
      for (int ni = 0; ni < 4; ++ni) {
        int j = n0 + wn * 64 + ni * 16 + (lane & 15);
        GA[(size_t)m * 2048 + j] = acc[mi][ni][r] + gx[(size_t)(m & 63) * 2048 + j];
      }
    }
  }
}

// ---- ALL 32 steps, one launch. Blocks 0..127: steppers in 4 independent groups
// (mq = bid&3 owns rows [mq*16, mq*16+16)); h crosses blocks via LLC (sc0 sc1
// stores + loads) so NO acquire fence -> Whb/GA stay L2-cached (r9's failure was
// the per-step buffer_inv refetching 1.7MB/step). B-frags + c + own-h in regs for
// all steps. Per-group 32-arrival barrier (padded counters, relaxed atomics).
// Blocks 128..255: W_out f32->bf16 under the step phase. ------------------------
__global__ void __launch_bounds__(256, 1) k_steps(
    unsigned short* __restrict__ h0, unsigned short* __restrict__ h1,
    const float* __restrict__ c0, const float* __restrict__ GA,
    const unsigned short* __restrict__ Whb, const int* __restrict__ lens,
    const int* __restrict__ base, unsigned short* __restrict__ Hm,
    int* __restrict__ bar, const float* __restrict__ W_out,
    unsigned short* __restrict__ Wob) {
  int tid = threadIdx.x, bid = blockIdx.x;
  if (bid >= 128) {  // W_out conversion on the otherwise-idle half of the chip
    for (long long i = ((long long)(bid - 128) * 256 + tid) * 8; i < 16384000LL;
         i += 128LL * 256 * 8) {
      float4 v0 = *(const float4*)(W_out + i);
      float4 v1 = *(const float4*)(W_out + i + 4);
      ushort8 o;
      o[0] = f2bf(v0.x); o[1] = f2bf(v0.y); o[2] = f2bf(v0.z); o[3] = f2bf(v0.w);
      o[4] = f2bf(v1.x); o[5] = f2bf(v1.y); o[6] = f2bf(v1.z); o[7] = f2bf(v1.w);
      *(ushort8*)(Wob + i) = o;
    }
    return;
  }
  int lane = tid & 63, w = tid >> 6;
  int lr = lane & 15, lk = lane >> 4;
  int mq = bid & 3, ug = bid >> 2;
  int r0 = mq * 16;
  int gate = lr >> 2, ul = lr & 3;
  int u = ug * 16 + w * 4 + ul;
  int L0 = lens[r0];  // group-wide step count (rows sorted desc)

  // B fragments: resident in VGPRs for ALL steps (the whole point)
  short8 bfr[16];
  {
    const unsigned short* Bp = Whb + ((size_t)gate * 512 + u) * 512 + lk * 8;
#pragma unroll
    for (int ks = 0; ks < 16; ++ks) bfr[ks] = *(const short8*)(Bp + ks * 32);
  }
  // c and own-h in registers (gate-0 lanes own cells (b = r0+lk*4+r, u))
  float cr[4];
  unsigned short hprev[4];
#pragma unroll
  for (int r = 0; r < 4; ++r) {
    int b = r0 + lk * 4 + r;
    cr[r] = c0[b * 512 + u];
    hprev[r] = h0[b * 512 + u];
  }
  // gate pre-adds for t=0
  float gv[4];
  {
    const float* gab = GA + (size_t)r0 * 2048 + gate * 512 + u;
#pragma unroll
    for (int r = 0; r < 4; ++r) gv[r] = gab[(size_t)(lk * 4 + r) * 2048];
  }

  for (int t = 0; t < L0; ++t) {
    const unsigned short* hin = (t & 1) ? h1 : h0;
    unsigned short* hout = (t & 1) ? h0 : h1;
    const unsigned short* Ap = hin + (size_t)(r0 + lr) * 512 + lk * 8;
    short8 afr[16];
#pragma unroll
    for (int ks = 0; ks < 16; ++ks) afr[ks] = ld16_llc(Ap + ks * 32);
    asm volatile("s_waitcnt vmcnt(0)" ::: "memory");
    __builtin_amdgcn_sched_barrier(0);
    f32x4 acc = (f32x4){0.f, 0.f, 0.f, 0.f};
#pragma unroll
    for (int ks = 0; ks < 16; ++ks)
      acc = __builtin_amdgcn_mfma_f32_16x16x32_bf16(afr[ks], bfr[ks], acc, 0, 0, 0);

    // prefetch next step's gate pre-adds (completes under the barrier)
    float gvn[4] = {0.f, 0.f, 0.f, 0.f};
    if (t + 1 < 32) {
      const float* gabn = GA + ((size_t)(t + 1) * 64 + r0) * 2048 + gate * 512 + u;
#pragma unroll
      for (int r = 0; r < 4; ++r) gvn[r] = gabn[(size_t)(lk * 4 + r) * 2048];
    }

#pragma unroll
    for (int r = 0; r < 4; ++r) {
      float v = acc[r] + gv[r];
      float av = (gate == 2) ? tanh_(v) : sigm(v);  // i,f,o: sigmoid; g: tanh
      float x4 = __shfl_xor(av, 4);
      float x8 = __shfl_xor(av, 8);
      float x12 = __shfl_xor(av, 12);
      float vi = (gate == 0) ? av : (gate == 1) ? x4 : (gate == 2) ? x8 : x12;
      float vf = (gate == 1) ? av : (gate == 0) ? x4 : (gate == 3) ? x8 : x12;
      float vg = (gate == 2) ? av : (gate == 3) ? x4 : (gate == 0) ? x8 : x12;
      float vo = (gate == 3) ? av : (gate == 2) ? x4 : (gate == 1) ? x8 : x12;
      if (gate == 0) {
        int b = r0 + lk * 4 + r;
        float cn = vf * cr[r] + vi * vg;
        float hn = vo * tanh_(cn);
        bool act = lens[b] > t;
        if (act) cr[r] = cn;
        unsigned short hbv = f2bf(hn);
        unsigned short hw = act ? hbv : hprev[r];
        st2_llc(hout + b * 512 + u, hw);  // write-through to LLC
        hprev[r] = hw;
        if (act) Hm[((size_t)(base[b] + t)) * 512 + u] = hbv;
      }
    }
#pragma unroll
    for (int r = 0; r < 4; ++r) gv[r] = gvn[r];

    if (t + 1 < L0) {  // group barrier: h_{t+1} fully in LLC before anyone reads
      asm volatile("s_waitcnt vmcnt(0)" ::: "memory");
      __syncthreads();
      if (tid == 0) {
        int* ctr = bar + (mq * 32 + t) * 16;  // 64B-padded counter
        __hip_atomic_fetch_add(ctr, 1, __ATOMIC_RELAXED,
                               __HIP_MEMORY_SCOPE_AGENT);
        while (__hip_atomic_load(ctr, __ATOMIC_RELAXED,
                                 __HIP_MEMORY_SCOPE_AGENT) < 32)
          __builtin_amdgcn_s_sleep(2);
      }
      __syncthreads();
    }
  }
}

// ---- packed GEMM, 512 threads, 128x256 tile (blocks 0..1999) + zero-fill of
// inactive rows (blocks 2000..2511) ----------------------------------------------
__global__ void __launch_bounds__(512) k_gemm(const unsigned short* __restrict__ Hm,
    const unsigned short* __restrict__ Wb, const float* __restrict__ b_out,
    const int* __restrict__ inv, const int* __restrict__ Pw,
    const int* __restrict__ lens, float* __restrict__ out) {
  int bid = blockIdx.x, tid = threadIdx.x;
  if (bid >= 2000) {
    int idx = bid - 2000;
    float4 z = {0.f, 0.f, 0.f, 0.f};
#pragma unroll
    for (int k = 0; k < 4; ++k) {
      int m = idx * 4 + k;
      int b = m >> 5, t = m & 31;
      if (lens[b] > t) continue;
      float* row = out + (size_t)m * 32000;
      for (int i = tid * 4; i < 32000; i += 2048) *(float4*)(row + i) = z;
    }
    return;
  }
  __shared__ alignas(16) char ldsbuf[49152];  // A 16KB | B 32KB
  char* ldsA = ldsbuf;
  char* ldsB = ldsbuf + 16384;
  int P = Pw[0];
  int sb = (bid & 7) * 250 + (bid >> 3);  // XCD chunks, 2000 % 8 == 0
  int mt = sb % 16, nt = sb / 16;         // mt fast: m-tiles share B slice
  int m0 = mt * 128, n0 = nt * 256;
  if (m0 >= P) return;
  int lane = tid & 63, w = tid >> 6;
  int wm = w >> 2, wn = w & 3;  // 2x4 waves, 64x64 out per wave
  f32x4 acc[4][4];
#pragma unroll
  for (int a = 0; a < 4; ++a)
#pragma unroll
    for (int bq = 0; bq < 4; ++bq) acc[a][bq] = (f32x4){0.f, 0.f, 0.f, 0.f};
  const unsigned short* Arow = Hm + (size_t)m0 * 512;
  const unsigned short* Brow = Wb + (size_t)n0 * 512;
  for (int kt = 0; kt < 8; ++kt) {
    int k0 = kt * 64;
    if (kt) __syncthreads();
#pragma unroll
    for (int j = 0; j < 2; ++j) {
      int ci = j * 512 + tid;
      int r = ci >> 3;
      int clog = ((ci & 7) << 4) ^ ((r & 7) << 4);
      gll16((const char*)(Arow + (size_t)r * 512 + k0) + clog, ldsA + ci * 16);
    }
#pragma unroll
    for (int j = 0; j < 4; ++j) {
      int ci = j * 512 + tid;
      int r = ci >> 3;
      int clog = ((ci & 7) << 4) ^ ((r & 7) << 4);
      gll16((const char*)(Brow + (size_t)r * 512 + k0) + clog, ldsB + ci * 16);
    }
    __syncthreads();
#pragma unroll
    for (int kk = 0; kk < 2; ++kk) {
      short8 af[4], bf[4];
      int cb = kk * 64 + (lane >> 4) * 16;
#pragma unroll
      for (int i = 0; i < 4; ++i) {
        int ar = wm * 64 + i * 16 + (lane & 15);
        af[i] = *(const short8*)(ldsA + ar * 128 + (cb ^ ((ar & 7) << 4)));
        int br = wn * 64 + i * 16 + (lane & 15);
        bf[i] = *(const short8*)(ldsB + br * 128 + (cb ^ ((br & 7) << 4)));
      }
#pragma unroll
      for (int mi = 0; mi < 4; ++mi)
#pragma unroll
        for (int ni = 0; ni < 4; ++ni)
          acc[mi][ni] = __builtin_amdgcn_mfma_f32_16x16x32_bf16(
              af[mi], bf[ni], acc[mi][ni], 0, 0, 0);
    }
  }
#pragma unroll
  for (int mi = 0; mi < 4; ++mi) {
    int pb = m0 + wm * 64 + mi * 16 + ((lane >> 4) << 2);
#pragma unroll
    for (int r = 0; r < 4; ++r) {
      int p = pb + r;
      if (p >= P) continue;
      size_t orow = (size_t)inv[p] * 32000;
#pragma unroll
      for (int ni = 0; ni < 4; ++ni) {
        int n = n0 + wn * 64 + ni * 16 + (lane & 15);
        out[orow + n] = acc[mi][ni][r] + b_out[n];
      }
    }
  }
}

extern "C" void kernel_launch(void* const* d_in, const int* in_sizes, int n_in,
                              void* d_out, int out_size, void* d_ws, size_t ws_size,
                              hipStream_t stream) {
  const float* x     = (const float*)d_in[0];
  const int*   ptar  = (const int*)d_in[1];
  const int*   tlen  = (const int*)d_in[2];
  const float* embed = (const float*)d_in[3];
  const float* W_h0  = (const float*)d_in[4];
  const float* b_h0  = (const float*)d_in[5];
  const float* W_c0  = (const float*)d_in[6];
  const float* b_c0  = (const float*)d_in[7];
  const float* W_ih  = (const float*)d_in[8];
  const float* W_hh  = (const float*)d_in[9];
  const float* b_ih  = (const float*)d_in[10];
  const float* b_hh  = (const float*)d_in[11];
  const float* W_out = (const float*)d_in[12];
  const float* b_out = (const float*)d_in[13];
  float* out = (float*)d_out;

  char* ws = (char*)d_ws;
  size_t off = 0;
  auto alloc = [&](size_t bytes) {
    void* p = ws + off;
    off += (bytes + 255) & ~(size_t)255;
    return p;
  };
  unsigned short* Wob = (unsigned short*)alloc(32000ull * 512 * 2);
  unsigned short* Hm  = (unsigned short*)alloc(2048ull * 512 * 2);
  unsigned short* h0b = (unsigned short*)alloc(64 * 512 * 2);
  unsigned short* h1b = (unsigned short*)alloc(64 * 512 * 2);
  float* cbuf = (float*)alloc(64 * 512 * 4);
  float* gx   = (float*)alloc(64 * 2048 * 4);
  int* sidx = (int*)alloc(64 * 4);
  int* lens = (int*)alloc(64 * 4);
  int* base = (int*)alloc(64 * 4);
  int* inv  = (int*)alloc(2048 * 4);
  int* Pw   = (int*)alloc(4);
  int* tok  = (int*)alloc(2048 * 4);
  int* bar  = (int*)alloc(2048 * 4);  // 4 groups x 32 steps x 16-int padding

  // scratch in d_out's prediction region (all dead before gemm/zf overwrite)
  float* GA = out;                                             // 2048*2048 f32
  unsigned short* Wpro  = (unsigned short*)(out + 4194304);    // 3072*512 bf16
  unsigned short* Wihb2 = (unsigned short*)(out + 4980736);    // 2048*256 bf16
  unsigned short* Whb   = (unsigned short*)(out + 5242880);    // 2048*512 bf16
  unsigned short* Eb    = (unsigned short*)(out + 5767168);    // 2048*256 bf16
  unsigned short* xsb   = (unsigned short*)(out + 6029312);    // 64*512 bf16
  float* tail = out + 65536000;                                // sorted_indices

  k_pre<<<1537, 256, 0, stream>>>(x, ptar, tlen, W_h0, W_c0, W_ih, W_hh,
                                  sidx, lens, base, inv, Pw, tok, xsb, tail,
                                  Wpro, Wihb2, Whb, bar);
  k_mid<<<304, 256, 0, stream>>>(xsb, Wpro, b_h0, b_c0, b_ih, b_hh, h0b, cbuf,
                                 gx, tok, embed, Eb);
  k_ga2<<<256, 256, 0, stream>>>(Eb, Wihb2, gx, GA);
  k_steps<<<256, 256, 0, stream>>>(h0b, h1b, cbuf, GA, Whb, lens, base, Hm,
                                   bar, W_out, Wob);
  k_gemm<<<2512, 512, 0, stream>>>(Hm, Wob, b_out, inv, Pw, lens, out);
  (void)in_sizes; (void)n_in; (void)out_size; (void)ws_size;
}